// Round 6
// baseline (141.750 us; speedup 1.0000x reference)
//
#include <hip/hip_runtime.h>

// GCN output = log_softmax(mean_n(x3) @ Wout + bout). All layers are linear
// up to the mean, so we back-propagate the pooling weights through the graph:
//   u2 = P^T 1, u1 = P^T u2, u0 = P^T u1   (P = D^-1/2 (A+I) D^-1/2)
//   v0 = sum_j u0[j]*feat[j];  v1 = v0@W0 + (sum u1)*b0
//   v2 = v1@W1 + (sum u2)*b1;  sum x3 = v2@W2 + N*b2; out = logsoftmax(head)
//
// R3: LDS-histogram scatter replaced global atomics (atomic RMW ~21 G/s cap).
// R4: 1024-thread final_kernel (W staged in LDS).
// R5: no memsets / no device atomics; 1 gather per edge (dinv factored out).
// R6: edges bucketed by src-group ONCE into packed 4B records
//     (src_local<<16 | dst); each hist_u pass reads 6.4 MB instead of
//     re-scanning 51.2 MB (4 groups x full edge list). Scatter uses
//     ballot-rank (1 LDS atomic per group per wave, not per lane).

#define FDIM 128
#define HSZ 12500          // nodes per LDS group (50 KB)
#define NBG 64             // hist blocks per group
#define NB_V0 128
#define S_FIX 16777216.0f
#define INV_S (1.0f / 16777216.0f)

// ---------------- bucketing ----------------

__global__ void __launch_bounds__(256)
count_kernel(const int* __restrict__ edges, int E, int e4,
             int* __restrict__ blockCnt) {
  __shared__ int cnt[4];
  if (threadIdx.x < 4) cnt[threadIdx.x] = 0;
  __syncthreads();
  int c0 = 0, c1 = 0, c2 = 0, c3 = 0;
  const int4* s4 = (const int4*)edges;
  for (int i = blockIdx.x * 256 + threadIdx.x; i < e4; i += 256 * 256) {
    int4 s = s4[i];
    int g;
    g = s.x / HSZ; if (g == 0) ++c0; else if (g == 1) ++c1; else if (g == 2) ++c2; else ++c3;
    g = s.y / HSZ; if (g == 0) ++c0; else if (g == 1) ++c1; else if (g == 2) ++c2; else ++c3;
    g = s.z / HSZ; if (g == 0) ++c0; else if (g == 1) ++c1; else if (g == 2) ++c2; else ++c3;
    g = s.w / HSZ; if (g == 0) ++c0; else if (g == 1) ++c1; else if (g == 2) ++c2; else ++c3;
  }
  if (blockIdx.x == 0) {
    for (int e = 4 * e4 + threadIdx.x; e < E; e += 256) {
      int g = edges[e] / HSZ;
      if (g == 0) ++c0; else if (g == 1) ++c1; else if (g == 2) ++c2; else ++c3;
    }
  }
  for (int o = 32; o > 0; o >>= 1) {
    c0 += __shfl_down(c0, o, 64);
    c1 += __shfl_down(c1, o, 64);
    c2 += __shfl_down(c2, o, 64);
    c3 += __shfl_down(c3, o, 64);
  }
  if ((threadIdx.x & 63) == 0) {
    atomicAdd(&cnt[0], c0);
    atomicAdd(&cnt[1], c1);
    atomicAdd(&cnt[2], c2);
    atomicAdd(&cnt[3], c3);
  }
  __syncthreads();
  if (threadIdx.x < 4) blockCnt[blockIdx.x * 4 + threadIdx.x] = cnt[threadIdx.x];
}

// blockOff[b][g] = base[g] + sum_{b'<b} blockCnt[b'][g]; meta = {base[4], tot[4]}
__global__ void __launch_bounds__(256)
scan_kernel(const int* __restrict__ blockCnt, int* __restrict__ blockOff,
            int* __restrict__ meta) {
  __shared__ int c[256 * 4];
  __shared__ int totS[4], baseS[4];
  for (int i = threadIdx.x; i < 256 * 4; i += 256) c[i] = blockCnt[i];
  __syncthreads();
  if (threadIdx.x < 4) {
    int g = threadIdx.x, run = 0;
    for (int b = 0; b < 256; ++b) {
      int v = c[b * 4 + g];
      c[b * 4 + g] = run;
      run += v;
    }
    totS[g] = run;
  }
  __syncthreads();
  if (threadIdx.x == 0) {
    int b = 0;
    for (int g = 0; g < 4; ++g) { baseS[g] = b; b += totS[g]; }
  }
  __syncthreads();
  for (int i = threadIdx.x; i < 256 * 4; i += 256)
    blockOff[i] = c[i] + baseS[i & 3];
  if (threadIdx.x < 4) {
    meta[threadIdx.x] = baseS[threadIdx.x];
    meta[4 + threadIdx.x] = totS[threadIdx.x];
  }
}

// scatter packed (src_local<<16 | dst) into per-group buckets; ballot-rank
__device__ __forceinline__ void push_edge(int s, int d, int lane, int w,
                                          int* off, volatile int* wbase,
                                          int* __restrict__ bucket) {
  int g = s / HSZ;
  unsigned long long m0 = __ballot(g == 0);
  unsigned long long m1 = __ballot(g == 1);
  unsigned long long m2 = __ballot(g == 2);
  unsigned long long m3 = __ballot(g == 3);
  unsigned long long mg = (g == 0) ? m0 : (g == 1) ? m1 : (g == 2) ? m2 : m3;
  #pragma unroll
  for (int k = 0; k < 4; ++k) {
    unsigned long long mk = (k == 0) ? m0 : (k == 1) ? m1 : (k == 2) ? m2 : m3;
    int ck = __popcll(mk);
    if (ck && lane == __ffsll((unsigned long long)mk) - 1)
      wbase[w * 4 + k] = atomicAdd(&off[k], ck);
  }
  int rank = __popcll(mg & ((1ull << lane) - 1ull));
  bucket[wbase[w * 4 + g] + rank] = ((s - g * HSZ) << 16) | d;
}

__global__ void __launch_bounds__(256)
scatter_kernel(const int* __restrict__ edges, int E, int e4,
               const int* __restrict__ blockOff, int* __restrict__ bucket) {
  __shared__ int off[4];
  __shared__ int wbase[4 * 4];                 // [wave][group]
  if (threadIdx.x < 4) off[threadIdx.x] = blockOff[blockIdx.x * 4 + threadIdx.x];
  __syncthreads();
  const int lane = threadIdx.x & 63;
  const int w = threadIdx.x >> 6;
  const int4* s4 = (const int4*)edges;
  const int4* d4 = (const int4*)(edges + E);
  for (int i = blockIdx.x * 256 + threadIdx.x; i < e4; i += 256 * 256) {
    int4 s = s4[i];
    int4 d = d4[i];
    push_edge(s.x, d.x, lane, w, off, wbase, bucket);
    push_edge(s.y, d.y, lane, w, off, wbase, bucket);
    push_edge(s.z, d.z, lane, w, off, wbase, bucket);
    push_edge(s.w, d.w, lane, w, off, wbase, bucket);
  }
  if (blockIdx.x == 0) {
    for (int e = 4 * e4 + threadIdx.x; e < E; e += 256) {
      push_edge(edges[e], edges[E + e], lane, w, off, wbase, bucket);
    }
  }
}

// ---------------- LDS-histogram scatter ----------------

__global__ void __launch_bounds__(1024)
hist_deg_kernel(const int* __restrict__ edges, int E, int e4, int N,
                int* __restrict__ partial) {
  __shared__ int h[HSZ];
  const int g = blockIdx.x / NBG;
  const int j = blockIdx.x - g * NBG;
  const int lo = g * HSZ;
  const int hi = min(N, lo + HSZ);
  const int hs = hi - lo;
  for (int i = threadIdx.x; i < hs; i += blockDim.x) h[i] = 0;
  __syncthreads();
  const int* dst = edges + E;
  const int4* dst4 = (const int4*)dst;
  for (int i = j * blockDim.x + threadIdx.x; i < e4; i += NBG * blockDim.x) {
    int4 d = dst4[i];
    if (d.x >= lo && d.x < hi) atomicAdd(&h[d.x - lo], 1);
    if (d.y >= lo && d.y < hi) atomicAdd(&h[d.y - lo], 1);
    if (d.z >= lo && d.z < hi) atomicAdd(&h[d.z - lo], 1);
    if (d.w >= lo && d.w < hi) atomicAdd(&h[d.w - lo], 1);
  }
  if (j == 0) {
    for (int e = 4 * e4 + threadIdx.x; e < E; e += blockDim.x) {
      int d = dst[e];
      if (d >= lo && d < hi) atomicAdd(&h[d - lo], 1);
    }
  }
  __syncthreads();
  int* out = partial + (size_t)blockIdx.x * HSZ;
  for (int i = threadIdx.x; i < hs; i += blockDim.x) out[i] = h[i];
}

__global__ void merge_dinv_kernel(const int* __restrict__ partial,
                                  float* __restrict__ dinv, int N) {
  int n = blockIdx.x * blockDim.x + threadIdx.x;
  if (n >= N) return;
  int g = n / HSZ;
  int off = n - g * HSZ;
  const int* p = partial + ((size_t)g * NBG) * HSZ + off;
  int s = 1;                                  // self loop
  for (int jj = 0; jj < NBG; ++jj) s += p[(size_t)jj * HSZ];
  dinv[n] = rsqrtf((float)s);
}

// bucketed hist: scatter w[dst] onto src_local within the group's slice
__global__ void __launch_bounds__(1024)
hist_u_kernel(const int* __restrict__ bucket, const int* __restrict__ meta,
              int N, const float* __restrict__ w,
              float* __restrict__ partial) {
  __shared__ float h[HSZ];
  const int g = blockIdx.x / NBG;
  const int j = blockIdx.x - g * NBG;
  const int lo = g * HSZ;
  const int hs = min(N, lo + HSZ) - lo;
  for (int i = threadIdx.x; i < hs; i += 1024) h[i] = 0.f;
  __syncthreads();
  const int base = meta[g];
  const int end = base + meta[4 + g];
  for (int i = base + j * 1024 + threadIdx.x; i < end; i += NBG * 1024) {
    int p = bucket[i];
    atomicAdd(&h[p >> 16], w[p & 0xFFFF]);
  }
  __syncthreads();
  float* out = partial + (size_t)blockIdx.x * HSZ;
  for (int i = threadIdx.x; i < hs; i += 1024) out[i] = h[i];
}

// u[n] = dinv[n]*(sum_j partial[j][n] + win[n]); optional uout/wout;
// per-block sum of u written to ssump[blockIdx] (no atomics, no memset).
__global__ void __launch_bounds__(256)
merge_u_kernel(const float* __restrict__ partial,
               const float* __restrict__ dinv,
               const float* __restrict__ win,
               float* __restrict__ uout,
               float* __restrict__ wout,
               float* __restrict__ ssump, int N) {
  __shared__ float red[4];
  int n = blockIdx.x * blockDim.x + threadIdx.x;
  float u = 0.f;
  if (n < N) {
    int g = n / HSZ;
    int off = n - g * HSZ;
    const float* p = partial + ((size_t)g * NBG) * HSZ + off;
    float s = 0.f;
    for (int jj = 0; jj < NBG; ++jj) s += p[(size_t)jj * HSZ];
    u = dinv[n] * (s + win[n]);               // self loop folded in
    if (uout) uout[n] = u;
    if (wout) wout[n] = dinv[n] * u;
  }
  if (ssump) {
    float a = u;
    for (int o = 32; o > 0; o >>= 1) a += __shfl_down(a, o, 64);
    if ((threadIdx.x & 63) == 0) red[threadIdx.x >> 6] = a;
    __syncthreads();
    if (threadIdx.x == 0)
      ssump[blockIdx.x] = red[0] + red[1] + red[2] + red[3];
  }
}

// per-block partials of v0[f] = sum_j u0[j]*feat[j][f]
__global__ void __launch_bounds__(1024)
v0_kernel(const float* __restrict__ feat, const float* __restrict__ u0,
          float* __restrict__ v0p, int N) {
  __shared__ float sh[8][FDIM];
  int f = threadIdx.x & (FDIM - 1);
  int r8 = threadIdx.x >> 7;                  // 0..7
  float acc = 0.f;
  for (int r = blockIdx.x * 8 + r8; r < N; r += NB_V0 * 8)
    acc += u0[r] * feat[(size_t)r * FDIM + f];
  sh[r8][f] = acc;
  __syncthreads();
  if (r8 == 0) {
    float s = acc;
    #pragma unroll
    for (int k = 1; k < 8; ++k) s += sh[k][f];
    v0p[(size_t)blockIdx.x * FDIM + f] = s;
  }
}

// 1024-thread tail: reduce v0p + ssum partials, 3 matvecs (W in LDS), head
__global__ void __launch_bounds__(1024)
final_kernel(const float* __restrict__ W0, const float* __restrict__ b0,
             const float* __restrict__ W1, const float* __restrict__ b1,
             const float* __restrict__ W2, const float* __restrict__ b2,
             const float* __restrict__ Wout, const float* __restrict__ bout,
             const float* __restrict__ v0p, int nv0,
             const float* __restrict__ ssumpA,  // partials of sum(u2)
             const float* __restrict__ ssumpB,  // partials of sum(u1)
             int nss,
             float* __restrict__ out, int N) {
  __shared__ float Wl[FDIM * FDIM];          // 64 KB
  __shared__ float WoL[FDIM * 10];           // 5 KB
  __shared__ float va[FDIM], vb[FDIM];
  __shared__ float part[8][FDIM];
  __shared__ float red0[16], red1[16];
  __shared__ float shS1, shS2;               // sum u1, sum u2
  __shared__ float lg[10];
  const int t = threadIdx.x;
  const int f = t & (FDIM - 1);
  const int sl = t >> 7;                     // 0..7

  {
    const float4* w4 = (const float4*)W0;
    float4* l4 = (float4*)Wl;
    #pragma unroll
    for (int i = 0; i < 4; ++i) l4[t + i * 1024] = w4[t + i * 1024];
    if (t < (FDIM * 10) / 4) ((float4*)WoL)[t] = ((const float4*)Wout)[t];
  }
  float acc = 0.f;
  for (int j = sl; j < nv0; j += 8) acc += v0p[(size_t)j * FDIM + f];
  part[sl][f] = acc;
  {
    float a0 = 0.f, a1 = 0.f;
    for (int j = t; j < nss; j += 1024) { a0 += ssumpA[j]; a1 += ssumpB[j]; }
    for (int o = 32; o > 0; o >>= 1) {
      a0 += __shfl_down(a0, o, 64);
      a1 += __shfl_down(a1, o, 64);
    }
    if ((t & 63) == 0) { red0[t >> 6] = a0; red1[t >> 6] = a1; }
  }
  __syncthreads();
  if (sl == 0) {
    float s = 0.f;
    #pragma unroll
    for (int j = 0; j < 8; ++j) s += part[j][f];
    va[f] = s;
  }
  if (t == 0) {
    float x = 0.f, y = 0.f;
    #pragma unroll
    for (int i = 0; i < 16; ++i) { x += red0[i]; y += red1[i]; }
    shS2 = x; shS1 = y;
  }
  __syncthreads();

  // vb = va@W0 + s1*b0
  acc = 0.f;
  #pragma unroll
  for (int k = 0; k < 16; ++k) {
    int kk = sl * 16 + k;
    acc += va[kk] * Wl[kk * FDIM + f];
  }
  part[sl][f] = acc;
  __syncthreads();
  {
    const float4* w4 = (const float4*)W1;
    float4* l4 = (float4*)Wl;
    #pragma unroll
    for (int i = 0; i < 4; ++i) l4[t + i * 1024] = w4[t + i * 1024];
  }
  if (sl == 0) {
    float s = 0.f;
    #pragma unroll
    for (int j = 0; j < 8; ++j) s += part[j][f];
    vb[f] = s + shS1 * b0[f];
  }
  __syncthreads();

  // va = vb@W1 + s2*b1
  acc = 0.f;
  #pragma unroll
  for (int k = 0; k < 16; ++k) {
    int kk = sl * 16 + k;
    acc += vb[kk] * Wl[kk * FDIM + f];
  }
  part[sl][f] = acc;
  __syncthreads();
  {
    const float4* w4 = (const float4*)W2;
    float4* l4 = (float4*)Wl;
    #pragma unroll
    for (int i = 0; i < 4; ++i) l4[t + i * 1024] = w4[t + i * 1024];
  }
  if (sl == 0) {
    float s = 0.f;
    #pragma unroll
    for (int j = 0; j < 8; ++j) s += part[j][f];
    va[f] = s + shS2 * b1[f];
  }
  __syncthreads();

  // vb = (va@W2)/N + b2  (= pooled)
  acc = 0.f;
  #pragma unroll
  for (int k = 0; k < 16; ++k) {
    int kk = sl * 16 + k;
    acc += va[kk] * Wl[kk * FDIM + f];
  }
  part[sl][f] = acc;
  __syncthreads();
  if (sl == 0) {
    float s = 0.f;
    #pragma unroll
    for (int j = 0; j < 8; ++j) s += part[j][f];
    vb[f] = s / (float)N + b2[f];
  }
  __syncthreads();

  if (t < 10) {
    float a = 0.f;
    for (int k = 0; k < FDIM; ++k) a += vb[k] * WoL[k * 10 + t];
    lg[t] = a + bout[t];
  }
  __syncthreads();
  if (t == 0) {
    float m = lg[0];
    for (int q = 1; q < 10; ++q) m = fmaxf(m, lg[q]);
    float s = 0.f;
    for (int q = 0; q < 10; ++q) s += expf(lg[q] - m);
    float lse = logf(s);
    for (int q = 0; q < 10; ++q) out[q] = lg[q] - m - lse;
  }
}

// ---------------- fallback path (R2, proven): global atomics ----------------

__global__ void deg_kernel(const int* __restrict__ edges, int E, int M,
                           int* __restrict__ deg) {
  for (int e = blockIdx.x * blockDim.x + threadIdx.x; e < M;
       e += gridDim.x * blockDim.x) {
    int d = (e < E) ? edges[E + e] : (e - E);
    atomicAdd(&deg[d], 1);
  }
}

__global__ void dinv_kernel(const int* __restrict__ deg,
                            float* __restrict__ dinv, int N) {
  int i = blockIdx.x * blockDim.x + threadIdx.x;
  if (i < N) {
    float d = (float)deg[i];
    dinv[i] = (d > 0.f) ? rsqrtf(d) : 0.f;
  }
}

__global__ void upass_kernel(const int* __restrict__ edges, int E, int M,
                             const float* __restrict__ dinv,
                             const int* __restrict__ uin_q,
                             int* __restrict__ uout_q) {
  for (int e = blockIdx.x * blockDim.x + threadIdx.x; e < M;
       e += gridDim.x * blockDim.x) {
    int s, d;
    if (e < E) { s = edges[e]; d = edges[E + e]; }
    else       { s = e - E;    d = s; }
    float v = dinv[s] * dinv[d];
    if (uin_q) v *= (float)uin_q[d] * INV_S;
    atomicAdd(&uout_q[s], __float2int_rn(v * S_FIX));
  }
}

__global__ void sums_kernel(const int* __restrict__ u2q,
                            const int* __restrict__ u1q,
                            float* __restrict__ ssump, int N) {
  __shared__ float red[8];
  int i = blockIdx.x * blockDim.x + threadIdx.x;
  float a = 0.f, b = 0.f;
  if (i < N) { a = (float)u2q[i] * INV_S; b = (float)u1q[i] * INV_S; }
  for (int o = 32; o > 0; o >>= 1) {
    a += __shfl_down(a, o, 64);
    b += __shfl_down(b, o, 64);
  }
  if ((threadIdx.x & 63) == 0) {
    red[(threadIdx.x >> 6) * 2] = a;
    red[(threadIdx.x >> 6) * 2 + 1] = b;
  }
  __syncthreads();
  if (threadIdx.x == 0) {
    ssump[blockIdx.x] = red[0] + red[2] + red[4] + red[6];
    ssump[gridDim.x + blockIdx.x] = red[1] + red[3] + red[5] + red[7];
  }
}

__global__ void v0_fallback_kernel(const float* __restrict__ feat,
                                   const int* __restrict__ u0q,
                                   float* __restrict__ v0p, int N) {
  __shared__ float sh[2][FDIM];
  int f = threadIdx.x & (FDIM - 1);
  int r2 = threadIdx.x >> 7;
  float acc = 0.f;
  for (int r = blockIdx.x * 2 + r2; r < N; r += gridDim.x * 2)
    acc += ((float)u0q[r] * INV_S) * feat[(size_t)r * FDIM + f];
  sh[r2][f] = acc;
  __syncthreads();
  if (r2 == 0) v0p[(size_t)blockIdx.x * FDIM + f] = sh[0][f] + sh[1][f];
}

// ---------------- launch ----------------

extern "C" void kernel_launch(void* const* d_in, const int* in_sizes, int n_in,
                              void* d_out, int out_size, void* d_ws, size_t ws_size,
                              hipStream_t stream) {
  const float* feat = (const float*)d_in[0];
  const int*   edges = (const int*)d_in[1];
  const float* W0 = (const float*)d_in[2];
  const float* b0 = (const float*)d_in[3];
  const float* W1 = (const float*)d_in[4];
  const float* b1 = (const float*)d_in[5];
  const float* W2 = (const float*)d_in[6];
  const float* b2 = (const float*)d_in[7];
  const float* Wout = (const float*)d_in[8];
  const float* bout = (const float*)d_in[9];

  const int N = in_sizes[0] / FDIM;          // 50000
  const int E = in_sizes[1] / 2;             // 1.6M
  const int NG = (N + HSZ - 1) / HSZ;        // 4 groups
  const int e4 = E >> 2;
  const int mergeGrid = (N + 255) / 256;     // 196

  char* ws = (char*)d_ws;
  size_t nb = ((size_t)N * 4 + 511) & ~(size_t)511;
  size_t partB = ((size_t)NG * NBG * HSZ * 4 + 511) & ~(size_t)511;
  size_t v0pB = ((size_t)NB_V0 * FDIM * 4 + 511) & ~(size_t)511;
  size_t ssB = ((size_t)mergeGrid * 4 + 511) & ~(size_t)511;
  size_t bktB = ((size_t)E * 4 + 511) & ~(size_t)511;
  size_t need = partB + 4 * nb + v0pB + 2 * ssB + bktB + 16384;

  if (ws_size >= need && NG == 4) {
    // main path — no memsets, no device-scope atomics
    char* p = ws;
    void*  part = (void*)p;        p += partB;
    float* dinv = (float*)p;       p += nb;
    float* w2   = (float*)p;       p += nb;
    float* w1   = (float*)p;       p += nb;
    float* u0   = (float*)p;       p += nb;
    float* v0p  = (float*)p;       p += v0pB;
    float* ssA  = (float*)p;       p += ssB;   // per-block partials of sum u2
    float* ssB_ = (float*)p;       p += ssB;   // per-block partials of sum u1
    int*   bucket = (int*)p;       p += bktB;
    int*   blockCnt = (int*)p;     p += 4096;
    int*   blockOff = (int*)p;     p += 4096;
    int*   meta = (int*)p;                     // base[4], tot[4]

    count_kernel<<<256, 256, 0, stream>>>(edges, E, e4, blockCnt);
    scan_kernel<<<1, 256, 0, stream>>>(blockCnt, blockOff, meta);
    scatter_kernel<<<256, 256, 0, stream>>>(edges, E, e4, blockOff, bucket);
    hist_deg_kernel<<<NG * NBG, 1024, 0, stream>>>(edges, E, e4, N, (int*)part);
    merge_dinv_kernel<<<mergeGrid, 256, 0, stream>>>((const int*)part, dinv, N);
    hist_u_kernel<<<NG * NBG, 1024, 0, stream>>>(bucket, meta, N, dinv, (float*)part);
    merge_u_kernel<<<mergeGrid, 256, 0, stream>>>((const float*)part, dinv, dinv,
                                                  nullptr, w2, ssA, N);
    hist_u_kernel<<<NG * NBG, 1024, 0, stream>>>(bucket, meta, N, w2, (float*)part);
    merge_u_kernel<<<mergeGrid, 256, 0, stream>>>((const float*)part, dinv, w2,
                                                  nullptr, w1, ssB_, N);
    hist_u_kernel<<<NG * NBG, 1024, 0, stream>>>(bucket, meta, N, w1, (float*)part);
    merge_u_kernel<<<mergeGrid, 256, 0, stream>>>((const float*)part, dinv, w1,
                                                  u0, nullptr, nullptr, N);
    v0_kernel<<<NB_V0, 1024, 0, stream>>>(feat, u0, v0p, N);
    final_kernel<<<1, 1024, 0, stream>>>(W0, b0, W1, b1, W2, b2, Wout, bout,
                                         v0p, NB_V0, ssA, ssB_, mergeGrid,
                                         (float*)d_out, N);
  } else {
    // fallback (R2-style): global-atomic scatter
    const int M = E + N;
    int*   deg  = (int*)(ws);
    float* dinv = (float*)(ws + nb);
    int*   u2q  = (int*)(ws + 2 * nb);
    int*   u1q  = (int*)(ws + 3 * nb);
    int*   u0q  = (int*)(ws + 4 * nb);
    float* v0p  = (float*)(ws + 5 * nb);               // NB_V0*FDIM
    float* ssp  = (float*)(ws + 5 * nb + v0pB);        // 2*mergeGrid

    hipMemsetAsync(ws, 0, 5 * nb, stream);

    deg_kernel<<<2048, 256, 0, stream>>>(edges, E, M, deg);
    dinv_kernel<<<mergeGrid, 256, 0, stream>>>(deg, dinv, N);
    upass_kernel<<<2048, 256, 0, stream>>>(edges, E, M, dinv, nullptr, u2q);
    upass_kernel<<<2048, 256, 0, stream>>>(edges, E, M, dinv, u2q, u1q);
    upass_kernel<<<2048, 256, 0, stream>>>(edges, E, M, dinv, u1q, u0q);
    sums_kernel<<<mergeGrid, 256, 0, stream>>>(u2q, u1q, ssp, N);
    v0_fallback_kernel<<<NB_V0, 256, 0, stream>>>(feat, u0q, v0p, N);
    final_kernel<<<1, 1024, 0, stream>>>(W0, b0, W1, b1, W2, b2, Wout, bout,
                                         v0p, NB_V0, ssp, ssp + mergeGrid,
                                         mergeGrid, (float*)d_out, N);
  }
}